// Round 10
// baseline (324.815 us; speedup 1.0000x reference)
//
#include <hip/hip_runtime.h>
#include <hip/hip_fp16.h>

#define NEG_SLOPE 0.1f
__device__ __forceinline__ float lrelu(float v) { return fmaxf(v, NEG_SLOPE * v); }

constexpr int CAP = 8704;   // per-bucket capacity (mean 6330 + 24-align pads); == 17*512
constexpr int EPB = 8192;   // edges per bin block (16 per thread, 512 threads)

typedef __attribute__((ext_vector_type(8))) short short8;   // 8 bf16 (4 VGPRs)
typedef __attribute__((ext_vector_type(4))) float f32x4;    // MFMA accum
typedef __attribute__((ext_vector_type(2))) float f32x2;    // packed v_pk_add_f32
typedef __attribute__((ext_vector_type(4))) int i32x4;      // clang vec (nontemporal-ok)

__device__ __forceinline__ unsigned short f2bf(float f) {   // RNE
    union { float f; unsigned u; } v; v.f = f;
    const unsigned r = v.u + 0x7FFF + ((v.u >> 16) & 1);
    return (unsigned short)(r >> 16);
}
__device__ __forceinline__ float bf2f(unsigned short h) {
    union { unsigned u; float f; } v; v.u = ((unsigned)h) << 16;
    return v.f;
}

__device__ __forceinline__ f32x2 cv2(unsigned u) {
    union { unsigned v; __half2 h; } cv; cv.v = u;
    const float2 ff = __half22float2(cv.h);
    f32x2 r; r.x = ff.x; r.y = ff.y; return r;
}

// ---------------------------------------------------------------------------
// Encoder (+fused prep in blocks 0..255). Unchanged.
// ---------------------------------------------------------------------------
__global__ __launch_bounds__(256) void encoder_kernel(
        const float* __restrict__ pose,
        const float* __restrict__ views,
        const float* __restrict__ w1, const float* __restrict__ b1,
        const float* __restrict__ w2, const float* __restrict__ b2,
        const float* __restrict__ w_l1, const float* __restrict__ w_l2,
        const float* __restrict__ w_l3, const float* __restrict__ w_rel,
        const float* __restrict__ w_root,
        unsigned short* __restrict__ Wb1, unsigned short* __restrict__ Wb2,
        unsigned short* __restrict__ Wb3, unsigned short* __restrict__ Wg,
        int* __restrict__ gcur,
        unsigned short* __restrict__ xHi, unsigned short* __restrict__ xLo,
        __half* __restrict__ xh, int N)
{
    __shared__ float s_w1[81];
    __shared__ float s_b1[9];
    __shared__ float s_w2[27];
    __shared__ float s_b2[1];
    __shared__ float s_c1[4][9][80];   // [lnode][oc][(p&1)*40 + (p>>1)]

    const int t = threadIdx.x;

    if (blockIdx.x < 256) {
        const int i = blockIdx.x * 256 + t;
        Wb1[i] = f2bf(w_l1[i]);
        Wb2[i] = f2bf(w_l2[i]);
        Wb3[i] = f2bf(w_l3[i]);
        if (i < 40960) {   // Wg[256][160] = [w_rel|w_root|w_rel|w_root]
            const int m = i / 160, c = i % 160;
            const int k = c % 80;
            const float v = (k < 40) ? w_rel[m * 40 + k] : w_root[m * 40 + (k - 40)];
            Wg[i] = f2bf(v);
        }
        if (i < 1024) gcur[i] = 0;
        if (i < 40) xh[(size_t)N * 40 + i] = __float2half(0.f);
    }

    if (t < 81) s_w1[t] = w1[t];
    if (t >= 96 && t < 105) s_b1[t - 96] = b1[t - 96];
    if (t >= 128 && t < 155) s_w2[t - 128] = w2[t - 128];
    if (t == 240) s_b2[0] = b2[0];
    __syncthreads();

    const int nb = blockIdx.x * 4;

    #pragma unroll
    for (int pass = 0; pass < 2; pass++) {
        const int task = pass * 256 + t;
        if (task < 300) {
            const int ln = task / 75;
            const int p  = task % 75;
            const int n  = min(nb + ln, N - 1);
            const float* __restrict__ vin = views + (size_t)n * 453 + 2 * p;
            float e[3], o[3], e1[3];
            #pragma unroll
            for (int ic = 0; ic < 3; ic++) {
                const float* ci = vin + ic * 151;
                e[ic] = ci[0]; o[ic] = ci[1]; e1[ic] = ci[2];
            }
            const int didx = (p & 1) * 40 + (p >> 1);
            #pragma unroll
            for (int oc = 0; oc < 9; oc++) {
                float v = s_b1[oc];
                #pragma unroll
                for (int ic = 0; ic < 3; ic++)
                    v += s_w1[oc * 9 + ic * 3 + 0] * e[ic]
                       + s_w1[oc * 9 + ic * 3 + 1] * o[ic]
                       + s_w1[oc * 9 + ic * 3 + 2] * e1[ic];
                s_c1[ln][oc][didx] = lrelu(v);
            }
        }
    }
    __syncthreads();

    if (t < 160) {
        const int ln = t / 40, f = t % 40;
        const int n  = min(nb + ln, N - 1);
        float outv;
        if (f < 3) {
            outv = pose[(size_t)n * 3 + f];
        } else {
            const int ow = f - 3;
            float v = s_b2[0];
            #pragma unroll
            for (int ic = 0; ic < 9; ic++)
                v += s_w2[ic * 3 + 0] * s_c1[ln][ic][ow]
                   + s_w2[ic * 3 + 1] * s_c1[ln][ic][40 + ow]
                   + s_w2[ic * 3 + 2] * s_c1[ln][ic][ow + 1];
            outv = lrelu(v);
        }
        const unsigned short hi = f2bf(outv);
        const unsigned short lo = f2bf(outv - bf2f(hi));
        xHi[(size_t)n * 40 + f] = hi;
        xLo[(size_t)n * 40 + f] = lo;
        xh[(size_t)n * 40 + f] = __float2half(outv);
    }
}

// ---------------------------------------------------------------------------
// Coarse binning. Packed entry = src | dloc<<22 (src < 2^16). Unchanged.
// ---------------------------------------------------------------------------
__global__ __launch_bounds__(512) void bin_kernel(
        const int* __restrict__ ei, int* __restrict__ gcur,
        int* __restrict__ pairs, int E, int NB)
{
    __shared__ int s_hist[1024];
    __shared__ int s_loff[1024];
    __shared__ int s_base[1024];
    __shared__ int s_wave8[8];
    __shared__ int s_pk[EPB];                 // 32 KB
    __shared__ unsigned short s_bkt[EPB];     // 16 KB
    const int t = threadIdx.x;
    const int lane = t & 63, wid = t >> 6;    // 8 waves
    const int e0 = blockIdx.x * EPB + t * 16;
    const int tot = min(E - (int)blockIdx.x * EPB, EPB);

    for (int i = t; i < 1024; i += 512) s_hist[i] = 0;
    __syncthreads();

    int pk[16], mt[16];
    auto proc = [&](int j, int sv, int dv) {
        const int b = dv >> 6;
        const int r = atomicAdd(&s_hist[b], 1);
        pk[j] = sv | ((dv & 63) << 22);
        mt[j] = b | (r << 10);
    };

    if (e0 + 16 <= E) {
        #pragma unroll
        for (int q = 0; q < 4; q++) {
            const int4 sv = *(const int4*)(ei + e0 + 4 * q);
            const int4 dv = *(const int4*)(ei + E + e0 + 4 * q);
            proc(4 * q + 0, sv.x, dv.x);
            proc(4 * q + 1, sv.y, dv.y);
            proc(4 * q + 2, sv.z, dv.z);
            proc(4 * q + 3, sv.w, dv.w);
        }
    } else {
        #pragma unroll
        for (int j = 0; j < 16; j++) {
            mt[j] = -1;
            const int e = e0 + j;
            if (e < E) proc(j, ei[e], ei[E + e]);
        }
    }
    __syncthreads();

    // exclusive scan of s_hist[0..1023] -> s_loff
    int carry = 0;
    #pragma unroll
    for (int base = 0; base < 1024; base += 512) {
        const int i = base + t;
        const int v = s_hist[i];
        int sc = v;
        #pragma unroll
        for (int d = 1; d < 64; d <<= 1) {
            const int u = __shfl_up(sc, d);
            if (lane >= d) sc += u;
        }
        if (lane == 63) s_wave8[wid] = sc;
        __syncthreads();
        if (wid == 0) {
            int wv = (lane < 8) ? s_wave8[lane] : 0;
            #pragma unroll
            for (int d = 1; d < 8; d <<= 1) {
                const int u = __shfl_up(wv, d);
                if (lane >= d) wv += u;
            }
            if (lane < 8) s_wave8[lane] = wv;
        }
        __syncthreads();
        const int waveoff = (wid > 0) ? s_wave8[wid - 1] : 0;
        s_loff[i] = carry + waveoff + sc - v;
        const int chunk_tot = s_wave8[7];
        __syncthreads();
        carry += chunk_tot;
    }

    for (int i = t; i < NB; i += 512) {
        const int c = s_hist[i];
        if (c > 0) s_base[i] = atomicAdd(&gcur[i], c);
    }
    __syncthreads();

    #pragma unroll
    for (int j = 0; j < 16; j++) {
        if (mt[j] >= 0) {
            const int b = mt[j] & 1023;
            const int pos = s_loff[b] + (mt[j] >> 10);
            s_pk[pos] = pk[j];
            s_bkt[pos] = (unsigned short)b;
        }
    }
    __syncthreads();

    for (int i = t; i < tot; i += 512) {
        const int b = s_bkt[i];
        const int p = s_base[b] + (i - s_loff[b]);
        if (p < CAP) pairs[b * CAP + p] = s_pk[i];
    }
}

// ---------------------------------------------------------------------------
// FUSED sort + gather + GEMM chain. r10 change: gather processes NODE PAIRS
// jointly — 8x16B loads in flight (2 KB/CU outstanding vs 1 KB; Little's law
// said ~2.3 KB needed at ~200cy L2 latency) and half the latency exposures
// per node. Per-node chunk order unchanged -> bitwise-identical sums.
// ---------------------------------------------------------------------------
__device__ __forceinline__ int aswz(int row, int col) {   // aT swizzled ushort idx
    return row * 256 + (col ^ ((row & 7) << 3));
}

__device__ __forceinline__ void gload16(const void* g, void* l) {
    __builtin_amdgcn_global_load_lds(
        (const __attribute__((address_space(1))) unsigned int*)g,
        (__attribute__((address_space(3))) unsigned int*)l,
        16, 0, 0);
}

// stage the wave's own 32 rows of W[*, k0..k0+32) into its 2 private chunks;
// global source col-group pre-swizzled (r9)
__device__ __forceinline__ void stage_panel(const unsigned short* __restrict__ W,
                                            int wstride, int k0,
                                            unsigned short* buf, int wave, int lane)
{
    const int rbase = wave * 32 + (lane >> 2);
    const int cu = (((lane & 3) ^ ((lane >> 3) & 3))) * 8;
    #pragma unroll
    for (int j = 0; j < 2; j++) {
        const int row = rbase + j * 16;
        gload16(W + (size_t)row * wstride + k0 + cu,
                buf + (wave * 2 + j) * 512);
    }
}

__device__ __forceinline__ void gemm_layer(const unsigned short* __restrict__ aT,
                                           const unsigned short* __restrict__ W,
                                           int wstride, int K,
                                           unsigned short* __restrict__ sWb,
                                           int wave, int lane, int l16, int q,
                                           f32x4 acc[4][2])
{
    const int NP = K >> 5;                    // 32-wide k panels
    stage_panel(W, wstride, 0,  sWb,        wave, lane);
    stage_panel(W, wstride, 32, sWb + 8192, wave, lane);
    const int wro = (wave * 2) * 512 + l16 * 32 + (q ^ ((l16 >> 1) & 3)) * 8;

    for (int p = 0; p < NP; p++) {
        unsigned short* wb = sWb + (p & 1) * 8192;
        // counted wait: panel p's 2 loads done; panel p+1's 2 stay in flight
        if (p + 1 < NP) asm volatile("s_waitcnt vmcnt(2)" ::: "memory");
        else            asm volatile("s_waitcnt vmcnt(0)" ::: "memory");
        short8 af[4], wf[2];
        #pragma unroll
        for (int nt = 0; nt < 4; nt++)
            af[nt] = *(const short8*)(aT + aswz(nt * 16 + l16, p * 32 + q * 8));
        #pragma unroll
        for (int mt = 0; mt < 2; mt++)
            wf[mt] = *(const short8*)(wb + wro + mt * 512);
        if (p + 2 < NP) {
            // ds_reads of wb must land in regs before re-staging wb
            asm volatile("s_waitcnt lgkmcnt(0)" ::: "memory");
            __builtin_amdgcn_sched_barrier(0);
            stage_panel(W, wstride, (p + 2) * 32, wb, wave, lane);
        }
        #pragma unroll
        for (int nt = 0; nt < 4; nt++)
            #pragma unroll
            for (int mt = 0; mt < 2; mt++)
                acc[nt][mt] = __builtin_amdgcn_mfma_f32_16x16x32_bf16(af[nt], wf[mt], acc[nt][mt], 0, 0, 0);
    }
}

__device__ __forceinline__ void epi_to_lds(f32x4 acc[4][2], const float* __restrict__ b,
                                           unsigned short* __restrict__ aT,
                                           int wave, int l16, int q)
{
    float bias[2];
    #pragma unroll
    for (int mt = 0; mt < 2; mt++) bias[mt] = b[wave * 32 + mt * 16 + l16];
    #pragma unroll
    for (int nt = 0; nt < 4; nt++)
        #pragma unroll
        for (int r = 0; r < 4; r++)
            #pragma unroll
            for (int mt = 0; mt < 2; mt++) {
                const int row = nt * 16 + q * 4 + r;         // C/D: row=quad*4+reg
                const int col = wave * 32 + mt * 16 + l16;   // C/D: col=lane&15
                aT[aswz(row, col)] = f2bf(lrelu(acc[nt][mt][r] + bias[mt]));
            }
}

__global__ __launch_bounds__(512) void sg_gemm_kernel(
        const int* __restrict__ gcur,
        const int* __restrict__ pairs,
        const __half* __restrict__ xh,
        const unsigned short* __restrict__ xHi,
        const unsigned short* __restrict__ xLo,
        const unsigned short* __restrict__ Wg,
        const float* __restrict__ b_rel,
        const unsigned short* __restrict__ Wb1,
        const float* __restrict__ b_l1,
        const unsigned short* __restrict__ Wb2,
        const float* __restrict__ b_l2,
        const unsigned short* __restrict__ Wb3,
        const float* __restrict__ b_l3,
        const float* __restrict__ w_pred,
        const float* __restrict__ b_pred,
        float* __restrict__ out, int N)
{
    __shared__ __align__(16) unsigned short aT[64 * 256];   // 32 KB, XOR-swizzled
    __shared__ __align__(16) char uni[32768];               // sort scratch / sW dbuf
    unsigned short* s_sorted = (unsigned short*)uni;        // [CAP] 16-bit ids
    int* s_cnt = (int*)(uni + 17408);                       // [64]
    int* s_off = (int*)(uni + 17664);                       // [64]
    unsigned short* sWb = (unsigned short*)uni;             // GEMM phase view

    const int b = blockIdx.x;
    const int t = threadIdx.x;
    const int n0 = b * 64;
    const int wave = t >> 6, lane = t & 63, q = lane >> 4, l16 = lane & 15;
    const int cnt = min(gcur[b], CAP);
    const int* __restrict__ pr = pairs + (size_t)b * CAP;

    if (t < 64) s_cnt[t] = 0;

    // phase A: stage packed entries in regs + load x strips into aT
    int pk[17];
    {
        const i32x4* __restrict__ pr4 = (const i32x4*)pr;
        #pragma unroll
        for (int j = 0; j < 4; j++) {
            const int m = t + j * 512;
            const i32x4 v = __builtin_nontemporal_load(pr4 + m);
            const int e0 = m * 4;
            pk[4 * j + 0] = (e0 + 0 < cnt) ? v.x : -1;
            pk[4 * j + 1] = (e0 + 1 < cnt) ? v.y : -1;
            pk[4 * j + 2] = (e0 + 2 < cnt) ? v.z : -1;
            pk[4 * j + 3] = (e0 + 3 < cnt) ? v.w : -1;
        }
        const int m16 = 8192 + t;
        pk[16] = (m16 < cnt) ? __builtin_nontemporal_load(pr + m16) : -1;
    }
    for (int u = t; u < 640; u += 512) {      // xHi/xLo -> aT cols 40..79/120..159
        const int row = u / 10, c = (u % 10) * 4;
        const int srow = min(n0 + row, N - 1);
        const size_t off = (size_t)srow * 40 + c;
        *(ushort4*)(aT + aswz(row, 40 + c))  = *(const ushort4*)(xHi + off);
        *(ushort4*)(aT + aswz(row, 120 + c)) = *(const ushort4*)(xLo + off);
    }
    __syncthreads();

    // phase B: histogram; atomicAdd return IS the edge's rank within its node
    int rk[17];
    #pragma unroll
    for (int j = 0; j < 17; j++)
        if (pk[j] >= 0) rk[j] = atomicAdd(&s_cnt[pk[j] >> 22], 1);
    __syncthreads();

    if (t < 64) {   // phase C: wave 0 exclusive scan of 24-aligned counts
        const int c = s_cnt[t];
        const int p = ((c + 23) / 24) * 24;
        int sc = p;
        #pragma unroll
        for (int d = 1; d < 64; d <<= 1) {
            const int u = __shfl_up(sc, d);
            if (t >= d) sc += u;
        }
        s_off[t] = sc - p;
    }
    __syncthreads();

    if (t < 64) {   // pad fill: sentinel id N (zero row in xh)
        const int e0 = s_off[t] + s_cnt[t];
        const int e1 = s_off[t] + ((s_cnt[t] + 23) / 24) * 24;
        for (int i = e0; i < e1 && i < CAP; i++) s_sorted[i] = (unsigned short)N;
    }
    #pragma unroll
    for (int j = 0; j < 17; j++) {            // phase D: rank-addressed scatter
        if (pk[j] >= 0) {
            const int pos = s_off[pk[j] >> 22] + rk[j];
            if (pos < CAP) s_sorted[pos] = (unsigned short)(pk[j] & 0xFFFF);
        }
    }
    __syncthreads();

    // phase E: PAIRED gather. wave w handles local nodes w*8..w*8+7, two at a
    // time; 12 slots x 5 lanes, 16 B/lane; joint loop keeps 8 loads in flight.
    {
        const int slot = min(lane / 5, 11);
        const int f8 = lane % 5;
        const char* __restrict__ xb = (const char*)xh + f8 * 16;

        #pragma unroll 1
        for (int i = 0; i < 8; i += 2) {
            const int lnA = wave * 8 + i, lnB = lnA + 1;
            const int nA = n0 + lnA;
            if (nA >= N) break;               // wave-uniform
            const bool hasB = (n0 + lnB < N);
            const int cntpA = ((s_cnt[lnA] + 23) / 24) * 24;
            const int cntpB = hasB ? ((s_cnt[lnB] + 23) / 24) * 24 : 0;
            const unsigned short* __restrict__ srtA = s_sorted + s_off[lnA] + slot;
            const unsigned short* __restrict__ srtB = s_sorted + s_off[lnB] + slot;

            f32x2 A0 = {0.f, 0.f}, A1 = {0.f, 0.f}, A2 = {0.f, 0.f}, A3 = {0.f, 0.f};
            f32x2 B0 = {0.f, 0.f}, B1 = {0.f, 0.f}, B2 = {0.f, 0.f}, B3 = {0.f, 0.f};
            auto accA = [&](uint4 u) {
                A0 += cv2(u.x); A1 += cv2(u.y); A2 += cv2(u.z); A3 += cv2(u.w);
            };
            auto accB = [&](uint4 u) {
                B0 += cv2(u.x); B1 += cv2(u.y); B2 += cv2(u.z); B3 += cv2(u.w);
            };

            int eA = 0, eB = 0;
            #pragma unroll 1
            while (eA + 48 <= cntpA && eB + 48 <= cntpB) {   // 8 loads in flight
                const int a0 = srtA[eA] * 80,      a1 = srtA[eA + 12] * 80;
                const int a2 = srtA[eA + 24] * 80, a3 = srtA[eA + 36] * 80;
                const int b0 = srtB[eB] * 80,      b1 = srtB[eB + 12] * 80;
                const int b2 = srtB[eB + 24] * 80, b3 = srtB[eB + 36] * 80;
                const uint4 uA0 = *(const uint4*)(xb + a0);
                const uint4 uA1 = *(const uint4*)(xb + a1);
                const uint4 uA2 = *(const uint4*)(xb + a2);
                const uint4 uA3 = *(const uint4*)(xb + a3);
                const uint4 uB0 = *(const uint4*)(xb + b0);
                const uint4 uB1 = *(const uint4*)(xb + b1);
                const uint4 uB2 = *(const uint4*)(xb + b2);
                const uint4 uB3 = *(const uint4*)(xb + b3);
                accA(uA0); accA(uA1); accA(uA2); accA(uA3);
                accB(uB0); accB(uB1); accB(uB2); accB(uB3);
                eA += 48; eB += 48;
            }
            #pragma unroll 1
            while (eA + 48 <= cntpA) {                       // drain A 48s
                const int a0 = srtA[eA] * 80,      a1 = srtA[eA + 12] * 80;
                const int a2 = srtA[eA + 24] * 80, a3 = srtA[eA + 36] * 80;
                const uint4 u0 = *(const uint4*)(xb + a0);
                const uint4 u1 = *(const uint4*)(xb + a1);
                const uint4 u2 = *(const uint4*)(xb + a2);
                const uint4 u3 = *(const uint4*)(xb + a3);
                accA(u0); accA(u1); accA(u2); accA(u3);
                eA += 48;
            }
            #pragma unroll 1
            while (eA < cntpA) {                             // A 24-tail
                const int a0 = srtA[eA] * 80, a1 = srtA[eA + 12] * 80;
                const uint4 u0 = *(const uint4*)(xb + a0);
                const uint4 u1 = *(const uint4*)(xb + a1);
                accA(u0); accA(u1);
                eA += 24;
            }
            #pragma unroll 1
            while (eB + 48 <= cntpB) {                       // drain B 48s
                const int b0 = srtB[eB] * 80,      b1 = srtB[eB + 12] * 80;
                const int b2 = srtB[eB + 24] * 80, b3 = srtB[eB + 36] * 80;
                const uint4 u0 = *(const uint4*)(xb + b0);
                const uint4 u1 = *(const uint4*)(xb + b1);
                const uint4 u2 = *(const uint4*)(xb + b2);
                const uint4 u3 = *(const uint4*)(xb + b3);
                accB(u0); accB(u1); accB(u2); accB(u3);
                eB += 48;
            }
            #pragma unroll 1
            while (eB < cntpB) {                             // B 24-tail
                const int b0 = srtB[eB] * 80, b1 = srtB[eB + 12] * 80;
                const uint4 u0 = *(const uint4*)(xb + b0);
                const uint4 u1 = *(const uint4*)(xb + b1);
                accB(u0); accB(u1);
                eB += 24;
            }

            // fold 12 slots -> slot 0 (lanes 0..4); deltas preserve f8 (mod 5)
            #pragma unroll
            for (int st = 0; st < 2; st++) {
                const int d = st ? 15 : 30;
                A0.x += __shfl(A0.x, lane + d); A0.y += __shfl(A0.y, lane + d);
                A1.x += __shfl(A1.x, lane + d); A1.y += __shfl(A1.y, lane + d);
                A2.x += __shfl(A2.x, lane + d); A2.y += __shfl(A2.y, lane + d);
                A3.x += __shfl(A3.x, lane + d); A3.y += __shfl(A3.y, lane + d);
                B0.x += __shfl(B0.x, lane + d); B0.y += __shfl(B0.y, lane + d);
                B1.x += __shfl(B1.x, lane + d); B1.y += __shfl(B1.y, lane + d);
                B2.x += __shfl(B2.x, lane + d); B2.y += __shfl(B2.y, lane + d);
                B3.x += __shfl(B3.x, lane + d); B3.y += __shfl(B3.y, lane + d);
            }
            A0.x += __shfl(A0.x, lane + 5) + __shfl(A0.x, lane + 10);
            A0.y += __shfl(A0.y, lane + 5) + __shfl(A0.y, lane + 10);
            A1.x += __shfl(A1.x, lane + 5) + __shfl(A1.x, lane + 10);
            A1.y += __shfl(A1.y, lane + 5) + __shfl(A1.y, lane + 10);
            A2.x += __shfl(A2.x, lane + 5) + __shfl(A2.x, lane + 10);
            A2.y += __shfl(A2.y, lane + 5) + __shfl(A2.y, lane + 10);
            A3.x += __shfl(A3.x, lane + 5) + __shfl(A3.x, lane + 10);
            A3.y += __shfl(A3.y, lane + 5) + __shfl(A3.y, lane + 10);
            B0.x += __shfl(B0.x, lane + 5) + __shfl(B0.x, lane + 10);
            B0.y += __shfl(B0.y, lane + 5) + __shfl(B0.y, lane + 10);
            B1.x += __shfl(B1.x, lane + 5) + __shfl(B1.x, lane + 10);
            B1.y += __shfl(B1.y, lane + 5) + __shfl(B1.y, lane + 10);
            B2.x += __shfl(B2.x, lane + 5) + __shfl(B2.x, lane + 10);
            B2.y += __shfl(B2.y, lane + 5) + __shfl(B2.y, lane + 10);
            B3.x += __shfl(B3.x, lane + 5) + __shfl(B3.x, lane + 10);
            B3.y += __shfl(B3.y, lane + 5) + __shfl(B3.y, lane + 10);

            if (lane < 5) {
                {   // node A -> aT cols 0..39 / 80..119
                    const float av[8] = {A0.x, A0.y, A1.x, A1.y, A2.x, A2.y, A3.x, A3.y};
                    unsigned short h[8], l[8];
                    #pragma unroll
                    for (int j = 0; j < 8; j++) {
                        h[j] = f2bf(av[j]);
                        l[j] = f2bf(av[j] - bf2f(h[j]));
                    }
                    uint4 H, L;
                    H.x = h[0] | ((unsigned)h[1] << 16); H.y = h[2] | ((unsigned)h[3] << 16);
                    H.z = h[4] | ((unsigned)h[5] << 16); H.w = h[6] | ((unsigned)h[7] << 16);
                    L.x = l[0] | ((unsigned)l[1] << 16); L.y = l[2] | ((unsigned)l[3] << 16);
                    L.z = l[4] | ((unsigned)l[5] << 16); L.w = l[6] | ((unsigned)l[7] << 16);
                    *(uint4*)(aT + aswz(lnA, lane * 8))      = H;
                    *(uint4*)(aT + aswz(lnA, 80 + lane * 8)) = L;
                }
                if (hasB) {   // node B
                    const float av[8] = {B0.x, B0.y, B1.x, B1.y, B2.x, B2.y, B3.x, B3.y};
                    unsigned short h[8], l[8];
                    #pragma unroll
                    for (int j = 0; j < 8; j++) {
                        h[j] = f2bf(av[j]);
                        l[j] = f2bf(av[j] - bf2f(h[j]));
                    }
                    uint4 H, L;
                    H.x = h[0] | ((unsigned)h[1] << 16); H.y = h[2] | ((unsigned)h[3] << 16);
                    H.z = h[4] | ((unsigned)h[5] << 16); H.w = h[6] | ((unsigned)h[7] << 16);
                    L.x = l[0] | ((unsigned)l[1] << 16); L.y = l[2] | ((unsigned)l[3] << 16);
                    L.z = l[4] | ((unsigned)l[5] << 16); L.w = l[6] | ((unsigned)l[7] << 16);
                    *(uint4*)(aT + aswz(lnB, lane * 8))      = H;
                    *(uint4*)(aT + aswz(lnB, 80 + lane * 8)) = L;
                }
            }
        }
    }
    __syncthreads();   // sort state dead; uni becomes the W-panel dbuf

    // phase F: GEMM chain
    {   // layer 0: graphconv, K=160
        f32x4 acc[4][2] = {};
        gemm_layer(aT, Wg, 160, 160, sWb, wave, lane, l16, q, acc);
        __syncthreads();
        epi_to_lds(acc, b_rel, aT, wave, l16, q);
        __syncthreads();
    }
    {   // layer 1
        f32x4 acc[4][2] = {};
        gemm_layer(aT, Wb1, 256, 256, sWb, wave, lane, l16, q, acc);
        __syncthreads();
        epi_to_lds(acc, b_l1, aT, wave, l16, q);
        __syncthreads();
    }
    {   // layer 2
        f32x4 acc[4][2] = {};
        gemm_layer(aT, Wb2, 256, 256, sWb, wave, lane, l16, q, acc);
        __syncthreads();
        epi_to_lds(acc, b_l2, aT, wave, l16, q);
        __syncthreads();
    }
    {   // layer 3 + pred epilogue (h3 never leaves registers)
        f32x4 acc[4][2] = {};
        gemm_layer(aT, Wb3, 256, 256, sWb, wave, lane, l16, q, acc);

        float bias[2], wp[2];
        #pragma unroll
        for (int mt = 0; mt < 2; mt++) {
            const int col = wave * 32 + mt * 16 + l16;
            bias[mt] = b_l3[col];
            wp[mt] = w_pred[col];
        }
        // partials into the wave's PRIVATE sW chunk (its own panel-0 bytes)
        float* spw = (float*)(uni + wave * 2048);
        #pragma unroll
        for (int nt = 0; nt < 4; nt++)
            #pragma unroll
            for (int r = 0; r < 4; r++) {
                float p = 0.f;
                #pragma unroll
                for (int mt = 0; mt < 2; mt++)
                    p += lrelu(acc[nt][mt][r] + bias[mt]) * wp[mt];
                p += __shfl_xor(p, 1);
                p += __shfl_xor(p, 2);
                p += __shfl_xor(p, 4);
                p += __shfl_xor(p, 8);
                if (l16 == 0) spw[nt * 16 + q * 4 + r] = p;
            }
        __syncthreads();

        if (t < 64) {
            const int row = n0 + t;
            if (row < N) {
                float s = b_pred[0];
                #pragma unroll
                for (int w = 0; w < 8; w++)
                    s += ((const float*)(uni + w * 2048))[t];
                out[row] = s;
            }
        }
    }
}

// ---------------------------------------------------------------------------
extern "C" void kernel_launch(void* const* d_in, const int* in_sizes, int n_in,
                              void* d_out, int out_size, void* d_ws, size_t ws_size,
                              hipStream_t stream)
{
    const float* pose   = (const float*)d_in[0];
    const float* views  = (const float*)d_in[1];
    const int*   ei     = (const int*)d_in[2];
    const float* w_e1   = (const float*)d_in[3];
    const float* b_e1   = (const float*)d_in[4];
    const float* w_e2   = (const float*)d_in[5];
    const float* b_e2   = (const float*)d_in[6];
    const float* w_rel  = (const float*)d_in[7];
    const float* b_rel  = (const float*)d_in[8];
    const float* w_root = (const float*)d_in[9];
    const float* w_l1   = (const float*)d_in[10];
    const float* b_l1   = (const float*)d_in[11];
    const float* w_l2   = (const float*)d_in[12];
    const float* b_l2   = (const float*)d_in[13];
    const float* w_l3   = (const float*)d_in[14];
    const float* b_l3   = (const float*)d_in[15];
    const float* w_pred = (const float*)d_in[16];
    const float* b_pred = (const float*)d_in[17];
    float* out = (float*)d_out;

    const int N = in_sizes[0] / 3;        // 50000
    const int E = in_sizes[2] / 2;        // 4950000
    const int NB = (N + 63) >> 6;         // 782 buckets == GEMM row blocks

    // Workspace layout (agg buffers eliminated by the r8 fusion)
    unsigned short* xHi = (unsigned short*)d_ws;     // N*40 bf16
    unsigned short* xLo = xHi + (size_t)N * 40;      // N*40 bf16
    __half* xh = (__half*)(xLo + (size_t)N * 40);    // (N+1)*40 fp16; row N = 0
    int* pairs = (int*)(xh + (size_t)(N + 1) * 40 + 24);   // NB*CAP ints
    int* gcur  = pairs + (size_t)NB * CAP;           // 1024
    unsigned short* Wb1 = (unsigned short*)(gcur + 1024);  // 256*256
    unsigned short* Wb2 = Wb1 + 256 * 256;
    unsigned short* Wb3 = Wb2 + 256 * 256;
    unsigned short* Wg  = Wb3 + 256 * 256;           // 256*160

    encoder_kernel<<<(N + 3) / 4, 256, 0, stream>>>(
        pose, views, w_e1, b_e1, w_e2, b_e2,
        w_l1, w_l2, w_l3, w_rel, w_root,
        Wb1, Wb2, Wb3, Wg, gcur, xHi, xLo, xh, N);

    bin_kernel<<<(E + EPB - 1) / EPB, 512, 0, stream>>>(ei, gcur, pairs, E, NB);

    sg_gemm_kernel<<<NB, 512, 0, stream>>>(
        gcur, pairs, xh, xHi, xLo, Wg, b_rel,
        Wb1, b_l1, Wb2, b_l2, Wb3, b_l3,
        w_pred, b_pred, out, N);
}